// Round 3
// baseline (547.772 us; speedup 1.0000x reference)
//
#include <hip/hip_runtime.h>
#include <math.h>

#define BB 32
#define CC 512
#define DD 4096
#define HH 128

// ---------------------------------------------------------------------------
// Kernel 1: bitwise replica of np.mean(x, axis=2) fp32 — numpy pairwise sum,
// npyv/AVX512 path: recursive halving (4096→…→128, clean power-of-2 splits),
// within each 128-block 8 zmm accumulators = 8 chunks of 16:
//   sum = ((c0+c1)+(c2+c3))+((c4+c5)+(c6+c7))   [vector adds, lane-wise]
// then _mm512_reduce_add_ps horizontal tree: strides 8, 4, 2, 1.
// Block-combine tree is balanced binary over the 32 blocks in order.
// One wave per (b,c) row; addition is bitwise-commutative so only grouping
// matters — reproduced with explicit parens + xor-butterflies.
// ---------------------------------------------------------------------------
__global__ __launch_bounds__(64) void pool_mean_np(const float* __restrict__ x,
                                                   float* __restrict__ pooled) {
    const int row = blockIdx.x;                 // b*CC + c
    const float* __restrict__ xr = x + (size_t)row * DD;
    const int l = threadIdx.x;                  // 0..63
    const int r = l & 15;                       // lane within 16-float chunk
    const int q = l >> 4;                       // which of 4 concurrent blocks

    float s[8];
#pragma unroll
    for (int i = 0; i < 8; ++i) {
        const int blk = 4 * i + q;              // 128-elem block index 0..31
        const float* base = xr + 128 * blk + r;
        float x0 = base[0],   x1 = base[16],  x2 = base[32],  x3 = base[48];
        float x4 = base[64],  x5 = base[80],  x6 = base[96],  x7 = base[112];
        // 8 vector accumulators combine (lane-wise tree over chunks)
        float T = ((x0 + x1) + (x2 + x3)) + ((x4 + x5) + (x6 + x7));
        // _mm512_reduce_add_ps: strides 8, 4, 2, 1
        T += __shfl_xor(T, 8, 64);
        T += __shfl_xor(T, 4, 64);
        T += __shfl_xor(T, 2, 64);
        T += __shfl_xor(T, 1, 64);
        s[i] = T;                               // block sum B_{4i+q} (all lanes)
    }
    // balanced binary tree over blocks in order:
    // (B_{2m} + B_{2m+1}) via q bit0, then pairs via q bit1, then over i.
#pragma unroll
    for (int i = 0; i < 8; ++i) {
        s[i] += __shfl_xor(s[i], 16, 64);
        s[i] += __shfl_xor(s[i], 32, 64);
    }
    float t01 = s[0] + s[1], t23 = s[2] + s[3];
    float t45 = s[4] + s[5], t67 = s[6] + s[7];
    float tot = (t01 + t23) + (t45 + t67);
    if (l == 0) pooled[row] = tot / 4096.0f;    // /2^12: exact
}

// ---------------------------------------------------------------------------
// Kernel 2: fp32 MLP replicating numpy/OpenBLAS bit-for-bit.
// Layer 1 (K=512): OpenBLAS level3 driver K-blocks; for Q < K < 2Q it halves:
//   C = fmachain(k=0..255) + fmachain(k=256..511)   [one add], then + b1.
// Layer 2 (K=128 < Q): single sequential fmaf chain from 0, then + b2.
// LeakyReLU with 0.01f; sigmoid 1/(1+exp(-z)) with correctly-rounded fp32
// exp (via double) — monotone, matches np's elementwise exp ordering.
// Stable descending rank-count == jnp.argsort(-scores) (stable).
// ---------------------------------------------------------------------------
__global__ __launch_bounds__(512) void mlp_sort_np(
    const float* __restrict__ pooled,
    const float* __restrict__ W1, const float* __restrict__ b1,
    const float* __restrict__ W2, const float* __restrict__ b2,
    int* __restrict__ order) {
    const int b = blockIdx.x;
    const int t = threadIdx.x;

    __shared__ float p[CC];
    __shared__ float h[HH];
    __shared__ float s[CC];

    p[t] = pooled[b * CC + t];
    __syncthreads();

    if (t < HH) {
        const float* __restrict__ w = W1 + t * CC;
        float u = 0.0f, v = 0.0f;
        for (int c = 0; c < 256; ++c)   u = fmaf(p[c], w[c], u);
        for (int c = 256; c < 512; ++c) v = fmaf(p[c], w[c], v);
        float acc = u + v;                       // K-panel combine (256+256)
        float hv = acc + b1[t];
        h[t] = (hv >= 0.0f) ? hv : 0.01f * hv;   // LeakyReLU(0.01)
    }
    __syncthreads();

    {
        const float* __restrict__ w = W2 + t * HH;
        float acc = 0.0f;
        for (int k = 0; k < HH; ++k) acc = fmaf(h[k], w[k], acc);
        float z = acc + b2[t];
        float e = (float)exp(-(double)z);        // correctly-rounded fp32 exp
        s[t] = 1.0f / (1.0f + e);                // fp32 add + IEEE fp32 divide
    }
    __syncthreads();

    const float mine = s[t];
    int rank = 0;
    for (int j = 0; j < CC; ++j) {
        float v = s[j];
        rank += (v > mine) || (v == mine && j < t);
    }
    order[b * CC + rank] = t;
}

// ---------------------------------------------------------------------------
// Kernel 3: out[b,r,:] = x[b,r,:] + x[b, order[b,r], :]. float4 everywhere.
// Single fp32 add -> bitwise identical to reference once order matches.
// ---------------------------------------------------------------------------
__global__ __launch_bounds__(256) void gather_add_kernel(
    const float* __restrict__ x, const int* __restrict__ order,
    float* __restrict__ out) {
    const int row = blockIdx.x;  // b*CC + r
    const int b = row >> 9;      // CC == 512
    const int src = order[row];
    const float4* __restrict__ xi = (const float4*)(x + (size_t)row * DD);
    const float4* __restrict__ xs =
        (const float4*)(x + ((size_t)(b * CC + src)) * DD);
    float4* __restrict__ o = (float4*)(out + (size_t)row * DD);
    const int t = threadIdx.x;
#pragma unroll
    for (int i = 0; i < 4; ++i) {
        float4 a = xi[t + i * 256];
        float4 g = xs[t + i * 256];
        o[t + i * 256] = make_float4(a.x + g.x, a.y + g.y, a.z + g.z, a.w + g.w);
    }
}

extern "C" void kernel_launch(void* const* d_in, const int* in_sizes, int n_in,
                              void* d_out, int out_size, void* d_ws,
                              size_t ws_size, hipStream_t stream) {
    const float* x  = (const float*)d_in[0];
    const float* W1 = (const float*)d_in[1];
    const float* b1 = (const float*)d_in[2];
    const float* W2 = (const float*)d_in[3];
    const float* b2 = (const float*)d_in[4];
    float* out = (float*)d_out;

    // workspace: [pooled: 16384 f32][order: 16384 i32]
    float* pooled = (float*)d_ws;
    int* order = (int*)((char*)d_ws + (size_t)BB * CC * sizeof(float));

    pool_mean_np<<<BB * CC, 64, 0, stream>>>(x, pooled);
    mlp_sort_np<<<BB, 512, 0, stream>>>(pooled, W1, b1, W2, b2, order);
    gather_add_kernel<<<BB * CC, 256, 0, stream>>>(x, order, out);
}